// Round 9
// baseline (327.927 us; speedup 1.0000x reference)
//
#include <hip/hip_runtime.h>
#include <hip/hip_fp16.h>

#define CIN   64
#define COUT  128
#define HIN   128
#define WIN   128
#define HOUT  126
#define WOUT  126
#define HP    63
#define WP    63
#define NB    32
#define NG    16
#define EPS   1e-5f
#define KTOT  576            // 9 * 64, k = (kh*3+kw)*64 + ci

// LDS x-tile (f16): [4 rows][66 cols][cell = 64 ci f16 (128B) + 16B pad = 144B]
#define CELLB 144
#define NCOLT 66
#define ROWB  (NCOLT * CELLB)   // 9504
#define XBYTES (4 * ROWB)       // 38016
#define NTILE 126               // rp*2 + ct

// tiled y: [b][co][chunk(126)][row(2)][col(64)] ; chunk = 128 floats (512B)
#define YCHUNK 128
#define YPLANE (126 * YCHUNK)   // 16128 floats per (b,co)

typedef __attribute__((ext_vector_type(8))) _Float16 half8;
typedef __attribute__((ext_vector_type(4))) float f32x4;

// ---- weight prep: cw[co][ci][3][3] f32 -> wt[co][k] f16 hi/lo, k=(kh*3+kw)*64+ci
__global__ __launch_bounds__(256) void wprep_kernel(
    const float* __restrict__ cw, ushort* __restrict__ wh, ushort* __restrict__ wl)
{
    int idx = blockIdx.x * 256 + threadIdx.x;
    if (idx >= COUT * KTOT) return;
    int co = idx / KTOT, k = idx - co * KTOT;
    int khw = k >> 6, ci = k & 63;
    float v = cw[(co * CIN + ci) * 9 + khw];
    __half h = __float2half(v);
    __half l = __float2half(v - __half2float(h));
    wh[idx] = __half_as_ushort(h);
    wl[idx] = __half_as_ushort(l);
}

// ---- conv implicit GEMM: block = 2 out rows x 64 cols x 128 couts, 4 waves
// wave = 32 couts (2 mt) x 128 spatial (8 nt); weights prefetched 1 phase ahead
__global__ __launch_bounds__(256, 3) void conv_mfma_kernel(
    const float* __restrict__ x, const ushort* __restrict__ wt_hi,
    const ushort* __restrict__ wt_lo, const float* __restrict__ cb,
    float* __restrict__ y, float* __restrict__ partials)
{
    __shared__ char xs[XBYTES];
    __shared__ float wred[4][2][4][2];

    const int tid = threadIdx.x;
    // XCD swizzle: 4032 blocks = 8 XCDs x 504; each XCD gets 4 whole images
    const int bid = blockIdx.x;
    const int w   = (bid & 7) * 504 + (bid >> 3);
    const int b   = w / 126;
    const int r   = w - b * 126;
    const int rp  = r >> 1;            // 0..62 row pair
    const int ct  = r & 1;             // col tile
    const int r0x = rp * 2;            // first x row needed (<=124)

    const int l = tid & 63, wid = tid >> 6;   // wid: cout quarter (32 couts)
    const int l15 = l & 15, lhi = l >> 4;

    f32x4 acc[2][8];
#pragma unroll
    for (int mt = 0; mt < 2; ++mt)
#pragma unroll
        for (int nt = 0; nt < 8; ++nt)
            acc[mt][nt] = (f32x4){0.f, 0.f, 0.f, 0.f};

    const float* xb = x + (size_t)b * (CIN * HIN * WIN);

    // weight fragment base; phase p: cip=p/9, kh=(p%9)/3, kw=p%3
    const ushort* wbh = wt_hi + (size_t)(wid * 32 + l15) * KTOT + lhi * 8;
    const ushort* wbl = wt_lo + (size_t)(wid * 32 + l15) * KTOT + lhi * 8;

    half8 WH[2][2], WL[2][2];          // [buf][mt] ping-pong weight batch

#define WOFF(p, mt) ((mt) * 16 * KTOT + (((p) % 9) * 64) + ((p) / 9) * 32)
#define LOADW(p, buf)                                            \
    {                                                            \
        WH[buf][0] = *(const half8*)(wbh + WOFF(p, 0));          \
        WH[buf][1] = *(const half8*)(wbh + WOFF(p, 1));          \
        WL[buf][0] = *(const half8*)(wbl + WOFF(p, 0));          \
        WL[buf][1] = *(const half8*)(wbl + WOFF(p, 1));          \
    }

    LOADW(0, 0);   // overlap first weight batch with x staging

    // ---- stage full 64-ci x-tile as f16: tasks = cig(16) x row(4) x c4(17) = 1088
    for (int t = 0; t < 5; ++t) {
        int gid = t * 256 + tid;
        if (gid < 1088) {
            int c4  = gid % 17;
            int rr  = (gid / 17) & 3;
            int cig = gid / 68;                  // 0..15 (4-ci groups)
            int row = r0x + rr;                  // always < HIN
            bool colok = (ct == 0) | (c4 < 16);  // avoid OOB float4 at gcol=128
            f32x4 f[4];
            const float* xp = xb + (size_t)(cig * 4) * (HIN * WIN)
                            + row * WIN + ct * 64 + c4 * 4;
#pragma unroll
            for (int q = 0; q < 4; ++q) {
                if (colok)
                    f[q] = *(const f32x4*)(xp + q * (HIN * WIN));
                else
                    f[q] = (f32x4){0.f, 0.f, 0.f, 0.f};
            }
#pragma unroll
            for (int j = 0; j < 4; ++j) {
                int lc = c4 * 4 + j;
                if (lc < NCOLT) {
                    ushort h0 = __half_as_ushort(__float2half(f[0][j]));
                    ushort h1 = __half_as_ushort(__float2half(f[1][j]));
                    ushort h2 = __half_as_ushort(__float2half(f[2][j]));
                    ushort h3 = __half_as_ushort(__float2half(f[3][j]));
                    uint2 hp;
                    hp.x = (unsigned)h0 | ((unsigned)h1 << 16);
                    hp.y = (unsigned)h2 | ((unsigned)h3 << 16);
                    *(uint2*)(xs + (rr * NCOLT + lc) * CELLB + cig * 8) = hp;
                }
            }
        }
    }
    __syncthreads();

    // ---- K loop: 18 phases (cip,kh,kw); weights for p+1 prefetched during p
    const char* pb = xs + l15 * CELLB + lhi * 16;

#pragma unroll
    for (int p = 0; p < 18; ++p) {
        const int buf = p & 1;
        if (p < 17) LOADW(p + 1, buf ^ 1);

        const int cip = p / 9, kh = (p % 9) / 3, kw = p % 3;
        half8 bh[8];
#pragma unroll
        for (int nt = 0; nt < 8; ++nt)
            bh[nt] = *(const half8*)(pb + ((nt >> 2) + kh) * ROWB
                    + ((nt & 3) * 16 + kw) * CELLB + cip * 64);

        // all hi-term MFMAs first, then all lo-term: dependent pairs on the
        // same acc are separated by 15 independent MFMAs (no dep stalls)
#pragma unroll
        for (int mt = 0; mt < 2; ++mt)
#pragma unroll
            for (int nt = 0; nt < 8; ++nt)
                acc[mt][nt] = __builtin_amdgcn_mfma_f32_16x16x32_f16(
                    WH[buf][mt], bh[nt], acc[mt][nt], 0, 0, 0);
#pragma unroll
        for (int mt = 0; mt < 2; ++mt)
#pragma unroll
            for (int nt = 0; nt < 8; ++nt)
                acc[mt][nt] = __builtin_amdgcn_mfma_f32_16x16x32_f16(
                    WL[buf][mt], bh[nt], acc[mt][nt], 0, 0, 0);
    }
#undef LOADW
#undef WOFF

    // ---- epilogue: bias, store y (all rows valid), group partials
    float cbv[2][4];
#pragma unroll
    for (int mt = 0; mt < 2; ++mt)
#pragma unroll
        for (int r2 = 0; r2 < 4; ++r2)
            cbv[mt][r2] = cb[wid * 32 + mt * 16 + lhi * 4 + r2];

    float* ybase = y + (size_t)b * COUT * YPLANE
                 + (size_t)((rp * 2 + ct) * YCHUNK) + l15;

#pragma unroll
    for (int mt = 0; mt < 2; ++mt) {
        float s1 = 0.f, s2 = 0.f;
#pragma unroll
        for (int r2 = 0; r2 < 4; ++r2) {
            int co = wid * 32 + mt * 16 + lhi * 4 + r2;
            float* yp = ybase + (size_t)co * YPLANE;
#pragma unroll
            for (int nt = 0; nt < 8; ++nt) {
                float v = acc[mt][nt][r2] + cbv[mt][r2];
                yp[(nt >> 2) * 64 + (nt & 3) * 16] = v;
                if (ct * 64 + (nt & 3) * 16 + l15 < WOUT) { s1 += v; s2 += v * v; }
            }
        }
        // reduce over the 16 spatial lanes (same lhi => same couts)
#pragma unroll
        for (int d = 1; d < 16; d <<= 1) {
            s1 += __shfl_xor(s1, d);
            s2 += __shfl_xor(s2, d);
        }
        if (l15 == 0) {
            wred[wid][mt][lhi][0] = s1;
            wred[wid][mt][lhi][1] = s2;
        }
    }
    __syncthreads();

    if (tid < NG) {
        int g = tid;                     // couts [g*8, g*8+8)
        int gw = g >> 2, mt = (g >> 1) & 1, h = g & 1;
        float t1 = wred[gw][mt][h * 2][0] + wred[gw][mt][h * 2 + 1][0];
        float t2 = wred[gw][mt][h * 2][1] + wred[gw][mt][h * 2 + 1][1];
        size_t pidx = (((size_t)b * NG + g) * NTILE + (rp * 2 + ct)) * 2;
        partials[pidx + 0] = t1;
        partials[pidx + 1] = t2;
    }
}

__global__ void stats_kernel(const float* __restrict__ partials,
                             float* __restrict__ stats)
{
    int t = blockIdx.x * blockDim.x + threadIdx.x;
    if (t >= NB * NG) return;
    float s1 = 0.f, s2 = 0.f;
    for (int j = 0; j < NTILE; ++j) {
        s1 += partials[((size_t)t * NTILE + j) * 2 + 0];
        s2 += partials[((size_t)t * NTILE + j) * 2 + 1];
    }
    const float N = 8.f * HOUT * WOUT;
    float mean = s1 / N;
    float var = s2 / N - mean * mean;
    stats[t * 2 + 0] = mean;
    stats[t * 2 + 1] = rsqrtf(var + EPS);
}

__global__ __launch_bounds__(256) void pool_kernel(
    const float* __restrict__ y, const float* __restrict__ stats,
    const float* __restrict__ gw, const float* __restrict__ gb,
    const float* __restrict__ sc, float* __restrict__ out)
{
    int idx = blockIdx.x * 256 + threadIdx.x;
    if (idx >= NB * COUT * HP * WP) return;
    int owp = idx % WP;
    int t = idx / WP;
    int ohp = t % HP; t /= HP;
    int c = t % COUT;
    int b = t / COUT;
    int g = c >> 3;

    float mean = stats[(b * NG + g) * 2 + 0];
    float rstd = stats[(b * NG + g) * 2 + 1];
    float ga = rstd * gw[c] * sc[c];
    float gbb = (gb[c] - mean * rstd * gw[c]) * sc[c];

    // tiled y: chunk = ohp*2 + (owp>>5); rows (0,1) of chunk; col = (2*owp)&63
    int ct = owp >> 5, col = (2 * owp) & 63;
    const float* yp = y + (size_t)(b * COUT + c) * YPLANE
                    + (ohp * 2 + ct) * YCHUNK + col;
    float2 r0 = *reinterpret_cast<const float2*>(yp);
    float2 r1 = *reinterpret_cast<const float2*>(yp + 64);
    float v0 = fmaf(r0.x, ga, gbb);
    float v1 = fmaf(r0.y, ga, gbb);
    float v2 = fmaf(r1.x, ga, gbb);
    float v3 = fmaf(r1.y, ga, gbb);
    float m = fmaxf(fmaxf(v0, v1), fmaxf(v2, v3));
    out[idx] = fminf(fmaxf(m, 0.f), 1.f);
}

extern "C" void kernel_launch(void* const* d_in, const int* in_sizes, int n_in,
                              void* d_out, int out_size, void* d_ws, size_t ws_size,
                              hipStream_t stream)
{
    const float* x  = (const float*)d_in[0];
    const float* cw = (const float*)d_in[1];
    const float* cbias = (const float*)d_in[2];
    const float* gw = (const float*)d_in[3];
    const float* gb = (const float*)d_in[4];
    const float* sc = (const float*)d_in[5];
    float* out = (float*)d_out;

    // ws: y 264,241,152 B + partials 1,032,192 + stats 4,096 + weights 294,912
    //   = 265,572,352 B = 253.3 MiB < 256 MiB
    const size_t YSZ = (size_t)NB * COUT * YPLANE;               // 66,060,288 f32
    float* y        = (float*)d_ws;
    float* partials = y + YSZ;                                   // 32*16*126*2 f32
    float* stats    = partials + (size_t)NB * NG * NTILE * 2;    // 1024 f32
    ushort* wh      = (ushort*)(stats + 1024);                   // 128*576 f16
    ushort* wl      = wh + (size_t)COUT * KTOT;

    hipLaunchKernelGGL(wprep_kernel, dim3((COUT * KTOT + 255) / 256), dim3(256),
                       0, stream, cw, wh, wl);

    hipLaunchKernelGGL(conv_mfma_kernel, dim3(4032), dim3(256), 0, stream,
                       x, wh, wl, cbias, y, partials);

    hipLaunchKernelGGL(stats_kernel, dim3(2), dim3(256), 0, stream,
                       partials, stats);

    int total = NB * COUT * HP * WP;
    hipLaunchKernelGGL(pool_kernel, dim3((total + 255) / 256), dim3(256), 0, stream,
                       y, stats, gw, gb, sc, out);
}

// Round 10
// 285.788 us; speedup vs baseline: 1.1474x; 1.1474x over previous
//
#include <hip/hip_runtime.h>
#include <hip/hip_fp16.h>

#define CIN   64
#define COUT  128
#define HIN   128
#define WIN   128
#define HOUT  126
#define WOUT  126
#define HP    63
#define WP    63
#define NB    32
#define NG    16
#define EPS   1e-5f
#define KTOT  576            // 9 * 64, k = (kh*3+kw)*64 + ci

// LDS x-tile (f16), per buffer: [4 rows][66 cols][cell = 32 ci f16 (64B) + 16B pad = 80B]
#define CELLB 80
#define NCOLT 66
#define ROWB  (NCOLT * CELLB)   // 5280
#define XHALF (4 * ROWB)        // 21120 per buffer
#define NTILE 126               // rp*2 + ct

// tiled y: [b][co][chunk(126)][row(2)][col(64)] ; chunk = 128 floats (512B)
#define YCHUNK 128
#define YPLANE (126 * YCHUNK)   // 16128 floats per (b,co)

typedef __attribute__((ext_vector_type(8))) _Float16 half8;
typedef __attribute__((ext_vector_type(4))) float f32x4;

// ---- weight prep: cw[co][ci][3][3] f32 -> wt[co][k] f16 hi/lo, k=(kh*3+kw)*64+ci
__global__ __launch_bounds__(256) void wprep_kernel(
    const float* __restrict__ cw, ushort* __restrict__ wh, ushort* __restrict__ wl)
{
    int idx = blockIdx.x * 256 + threadIdx.x;
    if (idx >= COUT * KTOT) return;
    int co = idx / KTOT, k = idx - co * KTOT;
    int khw = k >> 6, ci = k & 63;
    float v = cw[(co * CIN + ci) * 9 + khw];
    __half h = __float2half(v);
    __half l = __float2half(v - __half2float(h));
    wh[idx] = __half_as_ushort(h);
    wl[idx] = __half_as_ushort(l);
}

// ---- conv implicit GEMM: block = 2 rows x 64 cols x 128 couts, 8 waves,
// ci split in 2 chunks with LDS double-buffer; chunk-1 global loads issued
// into registers BEFORE chunk-0 compute (async-STAGE split).
__global__ __launch_bounds__(512, 4) void conv_mfma_kernel(
    const float* __restrict__ x, const ushort* __restrict__ wt_hi,
    const ushort* __restrict__ wt_lo, const float* __restrict__ cb,
    float* __restrict__ y, float* __restrict__ partials)
{
    __shared__ char xs[2 * XHALF];
    __shared__ float wred[8][4][2];

    const int tid = threadIdx.x;
    // XCD swizzle: 4032 blocks = 8 XCDs x 504; each XCD gets 4 whole images
    const int bid = blockIdx.x;
    const int w   = (bid & 7) * 504 + (bid >> 3);
    const int b   = w / 126;
    const int r   = w - b * 126;
    const int rp  = r >> 1;            // 0..62 row pair
    const int ct  = r & 1;             // col tile
    const int r0x = rp * 2;            // first x row needed (<=124; rows always valid)

    const int l = tid & 63, wid = tid >> 6;   // wid 0..7: 16-cout group
    const int l15 = l & 15, lhi = l >> 4;

    f32x4 acc[8];
#pragma unroll
    for (int nt = 0; nt < 8; ++nt) acc[nt] = (f32x4){0.f, 0.f, 0.f, 0.f};

    const float* xb = x + (size_t)b * (CIN * HIN * WIN);

    // main staging task (exactly 512): c4 = col quad (0..15), rr = row, cig = 4-ci group
    const int c4 = tid & 15, rr = (tid >> 4) & 3, cig = tid >> 6;
    const float* xmain = xb + (size_t)(cig * 4) * (HIN * WIN)
                       + (r0x + rr) * WIN + ct * 64 + c4 * 4;   // always in-bounds
    char* wmain = xs + rr * ROWB + (c4 * 4) * CELLB + cig * 8;

#define LOADMAIN(cip, f)                                                   \
    {                                                                      \
        _Pragma("unroll")                                                  \
        for (int q = 0; q < 4; ++q)                                        \
            f[q] = *(const f32x4*)(xmain + (size_t)((cip) * 32 + q) * (HIN * WIN)); \
    }

#define WRITEMAIN(f, buf)                                                  \
    {                                                                      \
        _Pragma("unroll")                                                  \
        for (int j = 0; j < 4; ++j) {                                      \
            ushort h0 = __half_as_ushort(__float2half(f[0][j]));           \
            ushort h1 = __half_as_ushort(__float2half(f[1][j]));           \
            ushort h2 = __half_as_ushort(__float2half(f[2][j]));           \
            ushort h3 = __half_as_ushort(__float2half(f[3][j]));           \
            uint2 hp;                                                      \
            hp.x = (unsigned)h0 | ((unsigned)h1 << 16);                    \
            hp.y = (unsigned)h2 | ((unsigned)h3 << 16);                    \
            *(uint2*)(wmain + (buf) * XHALF + j * CELLB) = hp;             \
        }                                                                  \
    }

    // tail: halo cols 64,65 (global cols ct*64+64/65; OOB for ct=1 -> zeros)
#define TAIL(cip, buf)                                                     \
    if (tid < 32) {                                                        \
        int trr = tid & 3, tcig = tid >> 2;                                \
        float2 g[4];                                                       \
        _Pragma("unroll")                                                  \
        for (int q = 0; q < 4; ++q) {                                      \
            if (ct == 0)                                                   \
                g[q] = *(const float2*)(xb                                 \
                      + (size_t)((cip) * 32 + tcig * 4 + q) * (HIN * WIN)  \
                      + (r0x + trr) * WIN + 64);                           \
            else g[q] = make_float2(0.f, 0.f);                             \
        }                                                                  \
        _Pragma("unroll")                                                  \
        for (int j = 0; j < 2; ++j) {                                      \
            float v0 = j ? g[0].y : g[0].x, v1 = j ? g[1].y : g[1].x;      \
            float v2 = j ? g[2].y : g[2].x, v3 = j ? g[3].y : g[3].x;      \
            uint2 hp;                                                      \
            hp.x = (unsigned)__half_as_ushort(__float2half(v0))            \
                 | ((unsigned)__half_as_ushort(__float2half(v1)) << 16);   \
            hp.y = (unsigned)__half_as_ushort(__float2half(v2))            \
                 | ((unsigned)__half_as_ushort(__float2half(v3)) << 16);   \
            *(uint2*)(xs + (buf) * XHALF + trr * ROWB + (64 + j) * CELLB   \
                      + tcig * 8) = hp;                                    \
        }                                                                  \
    }

    // weight fragment base (16-cout group wid)
    const ushort* wbh = wt_hi + (size_t)(wid * 16 + l15) * KTOT + lhi * 8;
    const ushort* wbl = wt_lo + (size_t)(wid * 16 + l15) * KTOT + lhi * 8;
    const char* pb = xs + l15 * CELLB + lhi * 16;

#define COMPUTE(buf, cip)                                                  \
    {                                                                      \
        _Pragma("unroll")                                                  \
        for (int khw = 0; khw < 9; ++khw) {                                \
            const int kh = khw / 3, kw = khw - kh * 3;                     \
            half8 wh_ = *(const half8*)(wbh + khw * 64 + (cip) * 32);      \
            half8 wl_ = *(const half8*)(wbl + khw * 64 + (cip) * 32);      \
            half8 bv[8];                                                   \
            _Pragma("unroll")                                              \
            for (int nt = 0; nt < 8; ++nt)                                 \
                bv[nt] = *(const half8*)(pb + (buf) * XHALF                \
                        + ((nt >> 2) + kh) * ROWB                          \
                        + ((nt & 3) * 16 + kw) * CELLB);                   \
            _Pragma("unroll")                                              \
            for (int nt = 0; nt < 8; ++nt)                                 \
                acc[nt] = __builtin_amdgcn_mfma_f32_16x16x32_f16(          \
                    wh_, bv[nt], acc[nt], 0, 0, 0);                        \
            _Pragma("unroll")                                              \
            for (int nt = 0; nt < 8; ++nt)                                 \
                acc[nt] = __builtin_amdgcn_mfma_f32_16x16x32_f16(          \
                    wl_, bv[nt], acc[nt], 0, 0, 0);                        \
        }                                                                  \
    }

    // ---- prologue: stage chunk 0 into buffer 0
    {
        f32x4 f0[4];
        LOADMAIN(0, f0);
        WRITEMAIN(f0, 0);
        TAIL(0, 0);
    }
    __syncthreads();

    // ---- pipelined: issue chunk-1 loads, compute chunk 0, write chunk 1
    {
        f32x4 f1[4];
        LOADMAIN(1, f1);
        __builtin_amdgcn_sched_barrier(0);   // pin loads above the compute
        COMPUTE(0, 0);
        WRITEMAIN(f1, 1);                    // vmcnt wait inserted by compiler
        TAIL(1, 1);
    }
    __syncthreads();
    COMPUTE(1, 1);

#undef LOADMAIN
#undef WRITEMAIN
#undef TAIL
#undef COMPUTE

    // ---- epilogue: bias, store y (all rows/cols of tile), group partials
    float cbv[4];
#pragma unroll
    for (int r2 = 0; r2 < 4; ++r2)
        cbv[r2] = cb[wid * 16 + lhi * 4 + r2];

    float* ybase = y + (size_t)b * COUT * YPLANE
                 + (size_t)((rp * 2 + ct) * YCHUNK) + l15;

    float s1 = 0.f, s2 = 0.f;
#pragma unroll
    for (int r2 = 0; r2 < 4; ++r2) {
        int co = wid * 16 + lhi * 4 + r2;
        float* yp = ybase + (size_t)co * YPLANE;
#pragma unroll
        for (int nt = 0; nt < 8; ++nt) {
            float v = acc[nt][r2] + cbv[r2];
            yp[(nt >> 2) * 64 + (nt & 3) * 16] = v;
            if (ct * 64 + (nt & 3) * 16 + l15 < WOUT) { s1 += v; s2 += v * v; }
        }
    }
#pragma unroll
    for (int d = 1; d < 16; d <<= 1) {
        s1 += __shfl_xor(s1, d);
        s2 += __shfl_xor(s2, d);
    }
    if (l15 == 0) {
        wred[wid][lhi][0] = s1;
        wred[wid][lhi][1] = s2;
    }
    __syncthreads();

    if (tid < NG) {
        int g = tid;                       // couts [8g, 8g+8)
        int gw = g >> 1, h = g & 1;
        float t1 = wred[gw][h * 2][0] + wred[gw][h * 2 + 1][0];
        float t2 = wred[gw][h * 2][1] + wred[gw][h * 2 + 1][1];
        size_t pidx = (((size_t)b * NG + g) * NTILE + (rp * 2 + ct)) * 2;
        partials[pidx + 0] = t1;
        partials[pidx + 1] = t2;
    }
}

__global__ void stats_kernel(const float* __restrict__ partials,
                             float* __restrict__ stats)
{
    int t = blockIdx.x * blockDim.x + threadIdx.x;
    if (t >= NB * NG) return;
    float s1 = 0.f, s2 = 0.f;
    for (int j = 0; j < NTILE; ++j) {
        s1 += partials[((size_t)t * NTILE + j) * 2 + 0];
        s2 += partials[((size_t)t * NTILE + j) * 2 + 1];
    }
    const float N = 8.f * HOUT * WOUT;
    float mean = s1 / N;
    float var = s2 / N - mean * mean;
    stats[t * 2 + 0] = mean;
    stats[t * 2 + 1] = rsqrtf(var + EPS);
}

__global__ __launch_bounds__(256) void pool_kernel(
    const float* __restrict__ y, const float* __restrict__ stats,
    const float* __restrict__ gw, const float* __restrict__ gb,
    const float* __restrict__ sc, float* __restrict__ out)
{
    int idx = blockIdx.x * 256 + threadIdx.x;
    if (idx >= NB * COUT * HP * WP) return;
    int owp = idx % WP;
    int t = idx / WP;
    int ohp = t % HP; t /= HP;
    int c = t % COUT;
    int b = t / COUT;
    int g = c >> 3;

    float mean = stats[(b * NG + g) * 2 + 0];
    float rstd = stats[(b * NG + g) * 2 + 1];
    float ga = rstd * gw[c] * sc[c];
    float gbb = (gb[c] - mean * rstd * gw[c]) * sc[c];

    // tiled y: chunk = ohp*2 + (owp>>5); rows (0,1) of chunk; col = (2*owp)&63
    int ct = owp >> 5, col = (2 * owp) & 63;
    const float* yp = y + (size_t)(b * COUT + c) * YPLANE
                    + (ohp * 2 + ct) * YCHUNK + col;
    float2 r0 = *reinterpret_cast<const float2*>(yp);
    float2 r1 = *reinterpret_cast<const float2*>(yp + 64);
    float v0 = fmaf(r0.x, ga, gbb);
    float v1 = fmaf(r0.y, ga, gbb);
    float v2 = fmaf(r1.x, ga, gbb);
    float v3 = fmaf(r1.y, ga, gbb);
    float m = fmaxf(fmaxf(v0, v1), fmaxf(v2, v3));
    out[idx] = fminf(fmaxf(m, 0.f), 1.f);
}

extern "C" void kernel_launch(void* const* d_in, const int* in_sizes, int n_in,
                              void* d_out, int out_size, void* d_ws, size_t ws_size,
                              hipStream_t stream)
{
    const float* x  = (const float*)d_in[0];
    const float* cw = (const float*)d_in[1];
    const float* cbias = (const float*)d_in[2];
    const float* gw = (const float*)d_in[3];
    const float* gb = (const float*)d_in[4];
    const float* sc = (const float*)d_in[5];
    float* out = (float*)d_out;

    // ws: y 264,241,152 B + partials 1,032,192 + stats 4,096 + weights 294,912
    //   = 265,572,352 B = 253.3 MiB < 256 MiB
    const size_t YSZ = (size_t)NB * COUT * YPLANE;               // 66,060,288 f32
    float* y        = (float*)d_ws;
    float* partials = y + YSZ;                                   // 32*16*126*2 f32
    float* stats    = partials + (size_t)NB * NG * NTILE * 2;    // 1024 f32
    ushort* wh      = (ushort*)(stats + 1024);                   // 128*576 f16
    ushort* wl      = wh + (size_t)COUT * KTOT;

    hipLaunchKernelGGL(wprep_kernel, dim3((COUT * KTOT + 255) / 256), dim3(256),
                       0, stream, cw, wh, wl);

    hipLaunchKernelGGL(conv_mfma_kernel, dim3(4032), dim3(512), 0, stream,
                       x, wh, wl, cbias, y, partials);

    hipLaunchKernelGGL(stats_kernel, dim3(2), dim3(256), 0, stream,
                       partials, stats);

    int total = NB * COUT * HP * WP;
    hipLaunchKernelGGL(pool_kernel, dim3((total + 255) / 256), dim3(256), 0, stream,
                       y, stats, gw, gb, sc, out);
}